// Round 2
// baseline (620.909 us; speedup 1.0000x reference)
//
#include <hip/hip_runtime.h>
#include <cstdint>

// Problem constants (fixed by the reference)
static constexpr int NN = 50000;   // nodes
static constexpr int NE = 800000;  // edges
static constexpr int NG = 512;     // graphs
static constexpr int NR = 19;      // relations
static constexpr int DD = 64;      // hidden dim
static constexpr int EMB = 65;
static constexpr int HID = 128;
static constexpr int FP = 166;

typedef __fp16 h2 __attribute__((ext_vector_type(2)));

__device__ __forceinline__ float dot2f(unsigned a, unsigned b, float c) {
#if __has_builtin(__builtin_amdgcn_fdot2)
    union { unsigned u; h2 h; } ua, ub;
    ua.u = a; ub.u = b;
    return __builtin_amdgcn_fdot2(ua.h, ub.h, c, false);
#else
    union { unsigned u; __fp16 h[2]; } ua, ub;
    ua.u = a; ub.u = b;
    return c + (float)ua.h[0] * (float)ub.h[0] + (float)ua.h[1] * (float)ub.h[1];
#endif
}

__device__ __forceinline__ unsigned pack2(float a, float b) {
#if __has_builtin(__builtin_amdgcn_cvt_pkrtz)
    union { h2 h; unsigned u; } r;
    r.h = __builtin_amdgcn_cvt_pkrtz(a, b);
    return r.u;
#else
    union { __fp16 h[2]; unsigned u; } r;
    r.h[0] = (__fp16)a; r.h[1] = (__fp16)b;
    return r.u;
#endif
}

// ---------------- degree ----------------
__global__ __launch_bounds__(256) void khistdeg(const int* __restrict__ dst, int* __restrict__ degi) {
    int e = blockIdx.x * 256 + threadIdx.x;
    if (e < NE) atomicAdd(&degi[dst[e]], 1);
}

__global__ __launch_bounds__(256) void kcvtdeg(const int* __restrict__ degi, float* __restrict__ degf) {
    int n = blockIdx.x * 256 + threadIdx.x;
    if (n < NN) degf[n] = (float)degi[n];
}

// ---------------- counting sort by etype ----------------
__global__ __launch_bounds__(256) void ksorthist(const int* __restrict__ et, int* __restrict__ cnt19) {
    __shared__ int lh[NR];
    if (threadIdx.x < NR) lh[threadIdx.x] = 0;
    __syncthreads();
    int e = blockIdx.x * 256 + threadIdx.x;
    if (e < NE) atomicAdd(&lh[et[e]], 1);
    __syncthreads();
    if (threadIdx.x < NR && lh[threadIdx.x]) atomicAdd(&cnt19[threadIdx.x], lh[threadIdx.x]);
}

__global__ void kscan19(const int* __restrict__ cnt19, int* __restrict__ ptr19, int* __restrict__ cur19) {
    if (threadIdx.x == 0 && blockIdx.x == 0) {
        int run = 0;
        for (int r = 0; r < NR; ++r) { ptr19[r] = run; cur19[r] = run; run += cnt19[r]; }
        ptr19[NR] = run;
    }
}

__global__ __launch_bounds__(256) void kscatter(const int* __restrict__ src, const int* __restrict__ dst,
                                                const int* __restrict__ et, int* __restrict__ cur19,
                                                unsigned* __restrict__ etsd) {
    __shared__ int lh[NR], lb[NR];
    int t = threadIdx.x;
    if (t < NR) lh[t] = 0;
    __syncthreads();
    int e = blockIdx.x * 256 + t;
    int myet = 0, loc = 0;
    if (e < NE) { myet = et[e]; loc = atomicAdd(&lh[myet], 1); }
    __syncthreads();
    if (t < NR && lh[t]) lb[t] = atomicAdd(&cur19[t], lh[t]);
    __syncthreads();
    if (e < NE) etsd[lb[myet] + loc] = (unsigned)src[e] | ((unsigned)dst[e] << 16);
}

// ---------------- layer 0: T[dst, et] += deg[src] ----------------
__global__ __launch_bounds__(256) void ktpass(const int* __restrict__ src, const int* __restrict__ dst,
                                              const int* __restrict__ et, const float* __restrict__ degf,
                                              float* __restrict__ T) {
    int e = blockIdx.x * 256 + threadIdx.x;
    if (e < NE) unsafeAtomicAdd(&T[dst[e] * NR + et[e]], degf[src[e]]);
}

// layer0 finalize: h0 = relu(T@W0 + deg*L0 + b0), emit packed f16
__global__ __launch_bounds__(256) void kf0(const float* __restrict__ T, const float* __restrict__ W0,
                                           const float* __restrict__ L0, const float* __restrict__ b0,
                                           const float* __restrict__ degf, unsigned* __restrict__ hpk0) {
    int lane = threadIdx.x & 63;
    int wid = __builtin_amdgcn_readfirstlane(threadIdx.x >> 6);
    int n = blockIdx.x * 4 + wid;
    if (n >= NN) return;
    float w0r[NR];
#pragma unroll
    for (int r = 0; r < NR; ++r) w0r[r] = W0[r * DD + lane];
    float acc = b0[lane] + degf[n] * L0[lane];
    const float* Trow = T + n * NR;
#pragma unroll
    for (int r = 0; r < NR; ++r) acc += Trow[r] * w0r[r];
    acc = fmaxf(acc, 0.f);
    float other = __shfl_xor(acc, 1);
    if ((lane & 1) == 0) hpk0[n * 32 + (lane >> 1)] = pack2(acc, other);
}

// ---------------- message pass: per-edge h[src]@W[et] -> atomicAdd agg[dst] ----------------
__global__ __launch_bounds__(256) void kmsg(const unsigned* __restrict__ etsd, const int* __restrict__ ptr19,
                                            const unsigned* __restrict__ hpk_in, const float* __restrict__ W,
                                            float* __restrict__ agg) {
    const int lane = threadIdx.x & 63;
    int wid = __builtin_amdgcn_readfirstlane(threadIdx.x >> 6);
    int gw = blockIdx.x * 4 + wid;
    const int nwaves = gridDim.x * 4;
    int chunk = (NE + nwaves - 1) / nwaves;
    int p0 = gw * chunk;
    int p1 = min(p0 + chunk, NE);
    if (p0 >= p1) return;

    int r = 0;
    while (ptr19[r + 1] <= p0) ++r;

    unsigned wreg[32];
    auto loadW = [&](int rr) {
        const float* wp = W + (size_t)rr * DD * DD;
#pragma unroll
        for (int kp = 0; kp < 32; ++kp) {
            float a = wp[(2 * kp) * DD + lane];
            float b = wp[(2 * kp + 1) * DD + lane];
            wreg[kp] = pack2(a, b);
        }
    };
    loadW(r);
    int rend = ptr19[r + 1];

    for (int p = p0; p < p1; ++p) {
        while (p >= rend) {
            ++r;
            rend = ptr19[r + 1];
            if (p < rend) loadW(r);
        }
        unsigned sd = etsd[p];
        int s = (int)(sd & 0xffffu);
        int d = (int)(sd >> 16);
        const unsigned* hr = hpk_in + s * 32;
        float a0 = 0.f, a1 = 0.f, a2 = 0.f, a3 = 0.f;
#pragma unroll
        for (int k4 = 0; k4 < 8; ++k4) {
            a0 = dot2f(hr[4 * k4 + 0], wreg[4 * k4 + 0], a0);
            a1 = dot2f(hr[4 * k4 + 1], wreg[4 * k4 + 1], a1);
            a2 = dot2f(hr[4 * k4 + 2], wreg[4 * k4 + 2], a2);
            a3 = dot2f(hr[4 * k4 + 3], wreg[4 * k4 + 3], a3);
        }
        float acc = (a0 + a1) + (a2 + a3);
        unsafeAtomicAdd(&agg[(size_t)d * DD + lane], acc);
    }
}

// ---------------- finalize: out = act(agg + h@L + b), emit f16-packed or emb ----------------
template <bool ACT, bool WRITE_EMB>
__global__ __launch_bounds__(256) void kfin(const float* __restrict__ agg, const unsigned* __restrict__ hpk_in,
                                            const float* __restrict__ L, const float* __restrict__ bvec,
                                            unsigned* __restrict__ hpk_out, float* __restrict__ embp,
                                            const float* __restrict__ nuc) {
    __shared__ unsigned Lp[32 * 64];
    for (int i = threadIdx.x; i < 2048; i += 256) {
        int kp = i >> 6, o = i & 63;
        Lp[i] = pack2(L[(2 * kp) * DD + o], L[(2 * kp + 1) * DD + o]);
    }
    __syncthreads();
    int lane = threadIdx.x & 63;
    int wid = __builtin_amdgcn_readfirstlane(threadIdx.x >> 6);
    int n = blockIdx.x * 4 + wid;
    if (n >= NN) return;
    float acc = agg[(size_t)n * DD + lane] + bvec[lane];
    const unsigned* hr = hpk_in + n * 32;
    float a0 = 0.f, a1 = 0.f, a2 = 0.f, a3 = 0.f;
#pragma unroll
    for (int k4 = 0; k4 < 8; ++k4) {
        a0 = dot2f(hr[4 * k4 + 0], Lp[(4 * k4 + 0) * 64 + lane], a0);
        a1 = dot2f(hr[4 * k4 + 1], Lp[(4 * k4 + 1) * 64 + lane], a1);
        a2 = dot2f(hr[4 * k4 + 2], Lp[(4 * k4 + 2) * 64 + lane], a2);
        a3 = dot2f(hr[4 * k4 + 3], Lp[(4 * k4 + 3) * 64 + lane], a3);
    }
    acc += (a0 + a1) + (a2 + a3);
    if (ACT) acc = fmaxf(acc, 0.f);
    if constexpr (WRITE_EMB) {
        embp[(size_t)n * EMB + lane] = acc;
        if (lane == 0) embp[(size_t)n * EMB + 64] = nuc[n];
    } else {
        float other = __shfl_xor(acc, 1);
        if ((lane & 1) == 0) hpk_out[n * 32 + (lane >> 1)] = pack2(acc, other);
    }
}

// ---------------- gate ----------------
__global__ __launch_bounds__(256) void kgate(const float* __restrict__ emb, const float* __restrict__ gatew,
                                             const float* __restrict__ gateb, float* __restrict__ gate) {
    int lane = threadIdx.x & 63;
    int wid = __builtin_amdgcn_readfirstlane(threadIdx.x >> 6);
    int n = blockIdx.x * 4 + wid;
    if (n >= NN) return;
    float v = emb[(size_t)n * EMB + lane] * gatew[lane];
#pragma unroll
    for (int s = 32; s >= 1; s >>= 1) v += __shfl_xor(v, s);
    if (lane == 0) gate[n] = v + emb[(size_t)n * EMB + 64] * gatew[64] + gateb[0];
}

// ---------------- graph boundaries ----------------
__global__ __launch_bounds__(256) void kgptr(const int* __restrict__ n2g, int* __restrict__ gptr) {
    int n = blockIdx.x * 256 + threadIdx.x;
    if (n >= NN) return;
    int g = n2g[n];
    int gp = (n == 0) ? -1 : n2g[n - 1];
    for (int gg = gp + 1; gg <= g; ++gg) gptr[gg] = n;
    if (n == NN - 1) {
        for (int gg = g + 1; gg <= NG; ++gg) gptr[gg] = NN;
    }
}

// ---------------- attention pooling ----------------
__global__ __launch_bounds__(128) void kpool(const int* __restrict__ gptr, const float* __restrict__ gate,
                                             const float* __restrict__ emb, float* __restrict__ fpb) {
    __shared__ float red[128];
    __shared__ float wch[128];
    int g = blockIdx.x;
    int t = threadIdx.x;
    int lo = gptr[g], hi = gptr[g + 1];

    float m = -INFINITY;
    for (int i = lo + t; i < hi; i += 128) m = fmaxf(m, gate[i]);
    red[t] = m;
    __syncthreads();
    for (int s = 64; s > 0; s >>= 1) {
        if (t < s) red[t] = fmaxf(red[t], red[t + s]);
        __syncthreads();
    }
    m = red[0];
    __syncthreads();

    float sum = 0.f;
    for (int i = lo + t; i < hi; i += 128) sum += __expf(gate[i] - m);
    red[t] = sum;
    __syncthreads();
    for (int s = 64; s > 0; s >>= 1) {
        if (t < s) red[t] += red[t + s];
        __syncthreads();
    }
    float denom = red[0];
    __syncthreads();

    float acc = 0.f;
    for (int base = lo; base < hi; base += 128) {
        int i = base + t;
        wch[t] = (i < hi) ? __expf(gate[i] - m) : 0.f;
        __syncthreads();
        int cnt = min(128, hi - base);
        if (t < EMB) {
            for (int j = 0; j < cnt; ++j) acc += wch[j] * emb[(size_t)(base + j) * EMB + t];
        }
        __syncthreads();
    }
    if (t < EMB) fpb[g * EMB + t] = (hi > lo) ? acc / denom : 0.f;
}

// ---------------- attributor MLP ----------------
__global__ __launch_bounds__(128) void kmlp(const float* __restrict__ fpb, const float* __restrict__ A1,
                                            const float* __restrict__ ab1, const float* __restrict__ A2,
                                            const float* __restrict__ ab2, float* __restrict__ out) {
    __shared__ float fv[EMB];
    __shared__ float h1[HID];
    int g = blockIdx.x;
    int t = threadIdx.x;
    if (t < EMB) fv[t] = fpb[g * EMB + t];
    __syncthreads();
    float a = ab1[t];
    for (int d = 0; d < EMB; ++d) a += fv[d] * A1[d * HID + t];
    h1[t] = fmaxf(a, 0.f);
    __syncthreads();
    for (int o = t; o < FP; o += HID) {
        float v = ab2[o];
        for (int k = 0; k < HID; ++k) v += h1[k] * A2[k * FP + o];
        out[(size_t)g * FP + o] = 1.f / (1.f + __expf(-v));
    }
}

extern "C" void kernel_launch(void* const* d_in, const int* in_sizes, int n_in,
                              void* d_out, int out_size, void* d_ws, size_t ws_size,
                              hipStream_t stream) {
    const int* src = (const int*)d_in[0];
    const int* dst = (const int*)d_in[1];
    const int* et = (const int*)d_in[2];
    const int* n2g = (const int*)d_in[3];
    const float* nuc = (const float*)d_in[4];
    const float* W0 = (const float*)d_in[5];
    const float* b0 = (const float*)d_in[6];
    const float* L0 = (const float*)d_in[7];
    const float* W1 = (const float*)d_in[8];
    const float* b1 = (const float*)d_in[9];
    const float* L1 = (const float*)d_in[10];
    const float* W2 = (const float*)d_in[11];
    const float* b2 = (const float*)d_in[12];
    const float* L2 = (const float*)d_in[13];
    const float* gatew = (const float*)d_in[14];
    const float* gateb = (const float*)d_in[15];
    const float* A1 = (const float*)d_in[16];
    const float* ab1 = (const float*)d_in[17];
    const float* A2 = (const float*)d_in[18];
    const float* ab2 = (const float*)d_in[19];

    float* out0 = (float*)d_out;                      // [G,166]
    float* embp = (float*)d_out + (size_t)NG * FP;    // [N,65]

    // workspace layout
    char* w = (char*)d_ws;
    size_t off = 0;
    auto alloc = [&](size_t bytes) { size_t r = off; off = (off + bytes + 255) & ~(size_t)255; return r; };
    size_t o_degi = alloc(NN * 4);
    size_t o_T    = alloc((size_t)NN * NR * 4);
    size_t o_cnt  = alloc(NR * 4);
    size_t zero_span = off;  // degi + T + cnt19 zeroed in one memset
    size_t o_ptr  = alloc((NR + 1) * 4);
    size_t o_cur  = alloc(NR * 4);
    size_t o_degf = alloc(NN * 4);
    size_t o_etsd = alloc((size_t)NE * 4);
    size_t o_hpk0 = alloc((size_t)NN * 32 * 4);
    size_t o_hpk1 = alloc((size_t)NN * 32 * 4);
    size_t o_agg  = alloc((size_t)NN * DD * 4);
    size_t o_gate = alloc(NN * 4);
    size_t o_gptr = alloc((NG + 1) * 4);
    size_t o_fpb  = alloc((size_t)NG * EMB * 4);
    (void)ws_size;

    int* degi = (int*)(w + o_degi);
    float* T = (float*)(w + o_T);
    int* cnt19 = (int*)(w + o_cnt);
    int* ptr19 = (int*)(w + o_ptr);
    int* cur19 = (int*)(w + o_cur);
    float* degf = (float*)(w + o_degf);
    unsigned* etsd = (unsigned*)(w + o_etsd);
    unsigned* hpk0 = (unsigned*)(w + o_hpk0);
    unsigned* hpk1 = (unsigned*)(w + o_hpk1);
    float* agg = (float*)(w + o_agg);
    float* gate = (float*)(w + o_gate);
    int* gptr = (int*)(w + o_gptr);
    float* fpb = (float*)(w + o_fpb);

    const int EB = (NE + 255) / 256;      // 3125
    const int NB = (NN + 255) / 256;      // 196
    const int NW = (NN + 3) / 4;          // 12500 (one node per wave, 4 waves/block)

    hipMemsetAsync(w, 0, zero_span, stream);

    khistdeg<<<EB, 256, 0, stream>>>(dst, degi);
    kcvtdeg<<<NB, 256, 0, stream>>>(degi, degf);
    ksorthist<<<EB, 256, 0, stream>>>(et, cnt19);
    kscan19<<<1, 64, 0, stream>>>(cnt19, ptr19, cur19);
    kscatter<<<EB, 256, 0, stream>>>(src, dst, et, cur19, etsd);
    ktpass<<<EB, 256, 0, stream>>>(src, dst, et, degf, T);
    kf0<<<NW, 256, 0, stream>>>(T, W0, L0, b0, degf, hpk0);

    // layer 1
    hipMemsetAsync(agg, 0, (size_t)NN * DD * 4, stream);
    kmsg<<<1024, 256, 0, stream>>>(etsd, ptr19, hpk0, W1, agg);
    kfin<true, false><<<NW, 256, 0, stream>>>(agg, hpk0, L1, b1, hpk1, nullptr, nullptr);

    // layer 2
    hipMemsetAsync(agg, 0, (size_t)NN * DD * 4, stream);
    kmsg<<<1024, 256, 0, stream>>>(etsd, ptr19, hpk1, W2, agg);
    kfin<false, true><<<NW, 256, 0, stream>>>(agg, hpk1, L2, b2, nullptr, embp, nuc);

    // pooling + MLP
    kgate<<<NW, 256, 0, stream>>>(embp, gatew, gateb, gate);
    kgptr<<<NB, 256, 0, stream>>>(n2g, gptr);
    kpool<<<NG, 128, 0, stream>>>(gptr, gate, embp, fpb);
    kmlp<<<NG, 128, 0, stream>>>(fpb, A1, ab1, A2, ab2, out0);
}

// Round 3
// 594.559 us; speedup vs baseline: 1.0443x; 1.0443x over previous
//
#include <hip/hip_runtime.h>
#include <cstdint>

// Problem constants (fixed by the reference)
static constexpr int NN = 50000;   // nodes
static constexpr int NE = 800000;  // edges
static constexpr int NG = 512;     // graphs
static constexpr int NR = 19;      // relations
static constexpr int DD = 64;      // hidden dim
static constexpr int EMB = 65;
static constexpr int HID = 128;
static constexpr int FP = 166;

typedef __fp16 h2 __attribute__((ext_vector_type(2)));
typedef _Float16 hf8 __attribute__((ext_vector_type(8)));
typedef float f32x4 __attribute__((ext_vector_type(4)));
typedef unsigned u32x4 __attribute__((ext_vector_type(4)));
typedef int i32x4 __attribute__((ext_vector_type(4)));

union U4H8 { u32x4 u; hf8 h; };

__device__ __forceinline__ hf8 as_hf8(u32x4 u) { U4H8 c; c.u = u; return c.h; }

__device__ __forceinline__ float dot2f(unsigned a, unsigned b, float c) {
    union { unsigned u; h2 h; } ua, ub;
    ua.u = a; ub.u = b;
    return __builtin_amdgcn_fdot2(ua.h, ub.h, c, false);
}

__device__ __forceinline__ unsigned pack2(float a, float b) {
    union { h2 h; unsigned u; } r;
    r.h = __builtin_amdgcn_cvt_pkrtz(a, b);
    return r.u;
}

// ---------------- degree ----------------
__global__ __launch_bounds__(256) void khistdeg(const int* __restrict__ dst, int* __restrict__ degi) {
    int e = blockIdx.x * 256 + threadIdx.x;
    if (e < NE) atomicAdd(&degi[dst[e]], 1);
}

__global__ __launch_bounds__(256) void kcvtdeg(const int* __restrict__ degi, float* __restrict__ degf) {
    int n = blockIdx.x * 256 + threadIdx.x;
    if (n < NN) degf[n] = (float)degi[n];
}

// ---------------- counting sort by etype (padded to multiples of 16) ----------------
__global__ __launch_bounds__(256) void ksorthist(const int* __restrict__ et, int* __restrict__ cnt19) {
    __shared__ int lh[NR];
    if (threadIdx.x < NR) lh[threadIdx.x] = 0;
    __syncthreads();
    int e = blockIdx.x * 256 + threadIdx.x;
    if (e < NE) atomicAdd(&lh[et[e]], 1);
    __syncthreads();
    if (threadIdx.x < NR && lh[threadIdx.x]) atomicAdd(&cnt19[threadIdx.x], lh[threadIdx.x]);
}

// pbase[r] = padded bin start (multiple of 16); batchptr[r] = pbase[r]/16
__global__ void kscan19(const int* __restrict__ cnt19, int* __restrict__ pbase,
                        int* __restrict__ cur19, int* __restrict__ batchptr) {
    if (threadIdx.x == 0 && blockIdx.x == 0) {
        int run = 0;
        for (int r = 0; r < NR; ++r) {
            pbase[r] = run; cur19[r] = run; batchptr[r] = run >> 4;
            run += (cnt19[r] + 15) & ~15;
        }
        pbase[NR] = run; batchptr[NR] = run >> 4;
    }
}

__global__ __launch_bounds__(256) void kscatter(const int* __restrict__ src, const int* __restrict__ dst,
                                                const int* __restrict__ et, int* __restrict__ cur19,
                                                int* __restrict__ srcp, int* __restrict__ dstp) {
    __shared__ int lh[NR], lb[NR];
    int t = threadIdx.x;
    if (t < NR) lh[t] = 0;
    __syncthreads();
    int e = blockIdx.x * 256 + t;
    int myet = 0, loc = 0;
    if (e < NE) { myet = et[e]; loc = atomicAdd(&lh[myet], 1); }
    __syncthreads();
    if (t < NR && lh[t]) lb[t] = atomicAdd(&cur19[t], lh[t]);
    __syncthreads();
    if (e < NE) {
        int pos = lb[myet] + loc;
        srcp[pos] = src[e];
        dstp[pos] = dst[e];
    }
}

// fill padding slots with sentinel (src=NN -> zero h row, dst=0 -> adds 0.0)
__global__ __launch_bounds__(512) void kpadfill(const int* __restrict__ cnt19, const int* __restrict__ pbase,
                                                int* __restrict__ srcp, int* __restrict__ dstp) {
    int t = threadIdx.x;
    int r = t >> 4, i = t & 15;
    if (r >= NR) return;
    int cnt = cnt19[r];
    int tail = pbase[r + 1] - pbase[r] - cnt;
    if (i < tail) {
        int pos = pbase[r] + cnt + i;
        srcp[pos] = NN;
        dstp[pos] = 0;
    }
}

// ---------------- pack W into per-lane MFMA B-fragments ----------------
// frag f = kh*4+ct; element: lane holds W[k = kh*32 + (lane>>4)*8 + j][ct*16 + (lane&15)], j=0..7
__global__ __launch_bounds__(256) void kwpack(const float* __restrict__ W, unsigned* __restrict__ wpk) {
    int t = blockIdx.x * 256 + threadIdx.x;
    if (t >= NR * 8 * 64) return;
    int lane = t & 63;
    int f = (t >> 6) & 7;
    int r = t >> 9;
    int kh = f >> 2, ct = f & 3;
    int kbase = kh * 32 + (lane >> 4) * 8;
    int col = ct * 16 + (lane & 15);
    const float* wr = W + (size_t)r * DD * DD;
    u32x4 out;
#pragma unroll
    for (int p = 0; p < 4; ++p)
        out[p] = pack2(wr[(kbase + 2 * p) * DD + col], wr[(kbase + 2 * p + 1) * DD + col]);
    *((u32x4*)wpk + t) = out;
}

// ---------------- layer 0: T[dst, et] += deg[src] ----------------
__global__ __launch_bounds__(256) void ktpass(const int* __restrict__ src, const int* __restrict__ dst,
                                              const int* __restrict__ et, const float* __restrict__ degf,
                                              float* __restrict__ T) {
    int e = blockIdx.x * 256 + threadIdx.x;
    if (e < NE) unsafeAtomicAdd(&T[dst[e] * NR + et[e]], degf[src[e]]);
}

// layer0 finalize: h0 = relu(T@W0 + deg*L0 + b0), emit packed f16
__global__ __launch_bounds__(256) void kf0(const float* __restrict__ T, const float* __restrict__ W0,
                                           const float* __restrict__ L0, const float* __restrict__ b0,
                                           const float* __restrict__ degf, unsigned* __restrict__ hpk0) {
    int lane = threadIdx.x & 63;
    int wid = __builtin_amdgcn_readfirstlane(threadIdx.x >> 6);
    int n = blockIdx.x * 4 + wid;
    if (n >= NN) return;
    float w0r[NR];
#pragma unroll
    for (int r = 0; r < NR; ++r) w0r[r] = W0[r * DD + lane];
    float acc = b0[lane] + degf[n] * L0[lane];
    const float* Trow = T + n * NR;
#pragma unroll
    for (int r = 0; r < NR; ++r) acc += Trow[r] * w0r[r];
    acc = fmaxf(acc, 0.f);
    float other = __shfl_xor(acc, 1);
    if ((lane & 1) == 0) hpk0[n * 32 + (lane >> 1)] = pack2(acc, other);
}

// ---------------- MFMA message pass ----------------
// batch = 16 same-relation edges; C[edge][col] = h[src] @ W[r]
__global__ __launch_bounds__(256) void kmsgm(const int* __restrict__ srcp, const int* __restrict__ dstp,
                                             const int* __restrict__ batchptr, const unsigned* __restrict__ hpk,
                                             const unsigned* __restrict__ wpk, float* __restrict__ agg) {
    const int lane = threadIdx.x & 63;
    int wid = __builtin_amdgcn_readfirstlane(threadIdx.x >> 6);
    int gw = blockIdx.x * 4 + wid;
    const int nwaves = gridDim.x * 4;
    const int totB = batchptr[NR];
    int chunk = (totB + nwaves - 1) / nwaves;
    int b0 = gw * chunk;
    int b1 = min(b0 + chunk, totB);
    if (b0 >= b1) return;

    int r = 0;
    while (batchptr[r + 1] <= b0) ++r;

    hf8 Bf[8];
    auto loadB = [&](int rr) {
        const u32x4* wq = (const u32x4*)wpk;
#pragma unroll
        for (int f = 0; f < 8; ++f) Bf[f] = as_hf8(wq[(rr * 8 + f) * 64 + lane]);
    };
    loadB(r);
    int rend = batchptr[r + 1];

    const int qk = lane >> 4;       // 0..3 k-group / row-group
    const int lm = lane & 15;       // edge-row (A) / out-col (B,C)

    for (int b = b0; b < b1; ++b) {
        while (b >= rend) {
            ++r;
            rend = batchptr[r + 1];
            if (b < rend) loadB(r);
        }
        int base = b << 4;
        int s = srcp[base + lm];
        const unsigned* hr = hpk + (size_t)s * 32;
        hf8 a0 = as_hf8(*(const u32x4*)(hr + (qk << 2)));          // k in [0,32)
        hf8 a1 = as_hf8(*(const u32x4*)(hr + 16 + (qk << 2)));     // k in [32,64)
        i32x4 d4 = *(const i32x4*)(dstp + base + (qk << 2));

        f32x4 acc0 = {0.f, 0.f, 0.f, 0.f};
        f32x4 acc1 = {0.f, 0.f, 0.f, 0.f};
        f32x4 acc2 = {0.f, 0.f, 0.f, 0.f};
        f32x4 acc3 = {0.f, 0.f, 0.f, 0.f};
        acc0 = __builtin_amdgcn_mfma_f32_16x16x32_f16(a0, Bf[0], acc0, 0, 0, 0);
        acc1 = __builtin_amdgcn_mfma_f32_16x16x32_f16(a0, Bf[1], acc1, 0, 0, 0);
        acc2 = __builtin_amdgcn_mfma_f32_16x16x32_f16(a0, Bf[2], acc2, 0, 0, 0);
        acc3 = __builtin_amdgcn_mfma_f32_16x16x32_f16(a0, Bf[3], acc3, 0, 0, 0);
        acc0 = __builtin_amdgcn_mfma_f32_16x16x32_f16(a1, Bf[4], acc0, 0, 0, 0);
        acc1 = __builtin_amdgcn_mfma_f32_16x16x32_f16(a1, Bf[5], acc1, 0, 0, 0);
        acc2 = __builtin_amdgcn_mfma_f32_16x16x32_f16(a1, Bf[6], acc2, 0, 0, 0);
        acc3 = __builtin_amdgcn_mfma_f32_16x16x32_f16(a1, Bf[7], acc3, 0, 0, 0);

        // C layout: col = lane&15, row = (lane>>4)*4 + reg  (rows = edges, d4[j] = dst of row)
#pragma unroll
        for (int j = 0; j < 4; ++j) {
            float* ag = agg + (size_t)d4[j] * DD + lm;
            unsafeAtomicAdd(ag +  0, acc0[j]);
            unsafeAtomicAdd(ag + 16, acc1[j]);
            unsafeAtomicAdd(ag + 32, acc2[j]);
            unsafeAtomicAdd(ag + 48, acc3[j]);
        }
    }
}

// ---------------- finalize: out = act(agg + h@L + b), emit f16-packed or emb ----------------
template <bool ACT, bool WRITE_EMB>
__global__ __launch_bounds__(256) void kfin(const float* __restrict__ agg, const unsigned* __restrict__ hpk_in,
                                            const float* __restrict__ L, const float* __restrict__ bvec,
                                            unsigned* __restrict__ hpk_out, float* __restrict__ embp,
                                            const float* __restrict__ nuc) {
    __shared__ unsigned Lp[32 * 64];
    for (int i = threadIdx.x; i < 2048; i += 256) {
        int kp = i >> 6, o = i & 63;
        Lp[i] = pack2(L[(2 * kp) * DD + o], L[(2 * kp + 1) * DD + o]);
    }
    __syncthreads();
    int lane = threadIdx.x & 63;
    int wid = __builtin_amdgcn_readfirstlane(threadIdx.x >> 6);
    int n = blockIdx.x * 4 + wid;
    if (n >= NN) return;
    float acc = agg[(size_t)n * DD + lane] + bvec[lane];
    const unsigned* hr = hpk_in + n * 32;
    float a0 = 0.f, a1 = 0.f, a2 = 0.f, a3 = 0.f;
#pragma unroll
    for (int k4 = 0; k4 < 8; ++k4) {
        a0 = dot2f(hr[4 * k4 + 0], Lp[(4 * k4 + 0) * 64 + lane], a0);
        a1 = dot2f(hr[4 * k4 + 1], Lp[(4 * k4 + 1) * 64 + lane], a1);
        a2 = dot2f(hr[4 * k4 + 2], Lp[(4 * k4 + 2) * 64 + lane], a2);
        a3 = dot2f(hr[4 * k4 + 3], Lp[(4 * k4 + 3) * 64 + lane], a3);
    }
    acc += (a0 + a1) + (a2 + a3);
    if (ACT) acc = fmaxf(acc, 0.f);
    if constexpr (WRITE_EMB) {
        embp[(size_t)n * EMB + lane] = acc;
        if (lane == 0) embp[(size_t)n * EMB + 64] = nuc[n];
    } else {
        float other = __shfl_xor(acc, 1);
        if ((lane & 1) == 0) hpk_out[n * 32 + (lane >> 1)] = pack2(acc, other);
    }
}

// ---------------- gate ----------------
__global__ __launch_bounds__(256) void kgate(const float* __restrict__ emb, const float* __restrict__ gatew,
                                             const float* __restrict__ gateb, float* __restrict__ gate) {
    int lane = threadIdx.x & 63;
    int wid = __builtin_amdgcn_readfirstlane(threadIdx.x >> 6);
    int n = blockIdx.x * 4 + wid;
    if (n >= NN) return;
    float v = emb[(size_t)n * EMB + lane] * gatew[lane];
#pragma unroll
    for (int s = 32; s >= 1; s >>= 1) v += __shfl_xor(v, s);
    if (lane == 0) gate[n] = v + emb[(size_t)n * EMB + 64] * gatew[64] + gateb[0];
}

// ---------------- graph boundaries ----------------
__global__ __launch_bounds__(256) void kgptr(const int* __restrict__ n2g, int* __restrict__ gptr) {
    int n = blockIdx.x * 256 + threadIdx.x;
    if (n >= NN) return;
    int g = n2g[n];
    int gp = (n == 0) ? -1 : n2g[n - 1];
    for (int gg = gp + 1; gg <= g; ++gg) gptr[gg] = n;
    if (n == NN - 1) {
        for (int gg = g + 1; gg <= NG; ++gg) gptr[gg] = NN;
    }
}

// ---------------- attention pooling ----------------
__global__ __launch_bounds__(128) void kpool(const int* __restrict__ gptr, const float* __restrict__ gate,
                                             const float* __restrict__ emb, float* __restrict__ fpb) {
    __shared__ float red[128];
    __shared__ float wch[128];
    int g = blockIdx.x;
    int t = threadIdx.x;
    int lo = gptr[g], hi = gptr[g + 1];

    float m = -INFINITY;
    for (int i = lo + t; i < hi; i += 128) m = fmaxf(m, gate[i]);
    red[t] = m;
    __syncthreads();
    for (int s = 64; s > 0; s >>= 1) {
        if (t < s) red[t] = fmaxf(red[t], red[t + s]);
        __syncthreads();
    }
    m = red[0];
    __syncthreads();

    float sum = 0.f;
    for (int i = lo + t; i < hi; i += 128) sum += __expf(gate[i] - m);
    red[t] = sum;
    __syncthreads();
    for (int s = 64; s > 0; s >>= 1) {
        if (t < s) red[t] += red[t + s];
        __syncthreads();
    }
    float denom = red[0];
    __syncthreads();

    float acc = 0.f;
    for (int base = lo; base < hi; base += 128) {
        int i = base + t;
        wch[t] = (i < hi) ? __expf(gate[i] - m) : 0.f;
        __syncthreads();
        int cnt = min(128, hi - base);
        if (t < EMB) {
            for (int j = 0; j < cnt; ++j) acc += wch[j] * emb[(size_t)(base + j) * EMB + t];
        }
        __syncthreads();
    }
    if (t < EMB) fpb[g * EMB + t] = (hi > lo) ? acc / denom : 0.f;
}

// ---------------- attributor MLP ----------------
__global__ __launch_bounds__(128) void kmlp(const float* __restrict__ fpb, const float* __restrict__ A1,
                                            const float* __restrict__ ab1, const float* __restrict__ A2,
                                            const float* __restrict__ ab2, float* __restrict__ out) {
    __shared__ float fv[EMB];
    __shared__ float h1[HID];
    int g = blockIdx.x;
    int t = threadIdx.x;
    if (t < EMB) fv[t] = fpb[g * EMB + t];
    __syncthreads();
    float a = ab1[t];
    for (int d = 0; d < EMB; ++d) a += fv[d] * A1[d * HID + t];
    h1[t] = fmaxf(a, 0.f);
    __syncthreads();
    for (int o = t; o < FP; o += HID) {
        float v = ab2[o];
        for (int k = 0; k < HID; ++k) v += h1[k] * A2[k * FP + o];
        out[(size_t)g * FP + o] = 1.f / (1.f + __expf(-v));
    }
}

extern "C" void kernel_launch(void* const* d_in, const int* in_sizes, int n_in,
                              void* d_out, int out_size, void* d_ws, size_t ws_size,
                              hipStream_t stream) {
    const int* src = (const int*)d_in[0];
    const int* dst = (const int*)d_in[1];
    const int* et = (const int*)d_in[2];
    const int* n2g = (const int*)d_in[3];
    const float* nuc = (const float*)d_in[4];
    const float* W0 = (const float*)d_in[5];
    const float* b0 = (const float*)d_in[6];
    const float* L0 = (const float*)d_in[7];
    const float* W1 = (const float*)d_in[8];
    const float* b1 = (const float*)d_in[9];
    const float* L1 = (const float*)d_in[10];
    const float* W2 = (const float*)d_in[11];
    const float* b2 = (const float*)d_in[12];
    const float* L2 = (const float*)d_in[13];
    const float* gatew = (const float*)d_in[14];
    const float* gateb = (const float*)d_in[15];
    const float* A1 = (const float*)d_in[16];
    const float* ab1 = (const float*)d_in[17];
    const float* A2 = (const float*)d_in[18];
    const float* ab2 = (const float*)d_in[19];
    (void)in_sizes; (void)n_in; (void)out_size; (void)ws_size;

    float* out0 = (float*)d_out;                      // [G,166]
    float* embp = (float*)d_out + (size_t)NG * FP;    // [N,65]

    const int NEP = NE + NR * 16;                     // padded edge capacity

    // workspace layout
    char* w = (char*)d_ws;
    size_t off = 0;
    auto alloc = [&](size_t bytes) { size_t r = off; off = (off + bytes + 255) & ~(size_t)255; return r; };
    // zeroed span: degi, T, cnt19, hpk0, hpk1 (sentinel row NN must be 0)
    size_t o_degi = alloc(NN * 4);
    size_t o_T    = alloc((size_t)NN * NR * 4);
    size_t o_cnt  = alloc(NR * 4);
    size_t o_hpk0 = alloc((size_t)(NN + 1) * 32 * 4);
    size_t o_hpk1 = alloc((size_t)(NN + 1) * 32 * 4);
    size_t zero_span = off;
    size_t o_pb   = alloc((NR + 1) * 4);
    size_t o_cur  = alloc(NR * 4);
    size_t o_bp   = alloc((NR + 1) * 4);
    size_t o_degf = alloc(NN * 4);
    size_t o_srcp = alloc((size_t)NEP * 4);
    size_t o_dstp = alloc((size_t)NEP * 4);
    size_t o_wpk1 = alloc((size_t)NR * 8 * 64 * 16);
    size_t o_wpk2 = alloc((size_t)NR * 8 * 64 * 16);
    size_t o_agg  = alloc((size_t)NN * DD * 4);
    size_t o_gate = alloc(NN * 4);
    size_t o_gptr = alloc((NG + 1) * 4);
    size_t o_fpb  = alloc((size_t)NG * EMB * 4);

    int* degi = (int*)(w + o_degi);
    float* T = (float*)(w + o_T);
    int* cnt19 = (int*)(w + o_cnt);
    unsigned* hpk0 = (unsigned*)(w + o_hpk0);
    unsigned* hpk1 = (unsigned*)(w + o_hpk1);
    int* pbase = (int*)(w + o_pb);
    int* cur19 = (int*)(w + o_cur);
    int* batchptr = (int*)(w + o_bp);
    float* degf = (float*)(w + o_degf);
    int* srcp = (int*)(w + o_srcp);
    int* dstp = (int*)(w + o_dstp);
    unsigned* wpk1 = (unsigned*)(w + o_wpk1);
    unsigned* wpk2 = (unsigned*)(w + o_wpk2);
    float* agg = (float*)(w + o_agg);
    float* gate = (float*)(w + o_gate);
    int* gptr = (int*)(w + o_gptr);
    float* fpb = (float*)(w + o_fpb);

    const int EB = (NE + 255) / 256;      // 3125
    const int NB = (NN + 255) / 256;      // 196
    const int NW = (NN + 3) / 4;          // 12500 (one node per wave, 4 waves/block)
    const int WPB = (NR * 8 * 64 + 255) / 256;

    hipMemsetAsync(w, 0, zero_span, stream);

    khistdeg<<<EB, 256, 0, stream>>>(dst, degi);
    kcvtdeg<<<NB, 256, 0, stream>>>(degi, degf);
    ksorthist<<<EB, 256, 0, stream>>>(et, cnt19);
    kscan19<<<1, 64, 0, stream>>>(cnt19, pbase, cur19, batchptr);
    kscatter<<<EB, 256, 0, stream>>>(src, dst, et, cur19, srcp, dstp);
    kpadfill<<<1, 512, 0, stream>>>(cnt19, pbase, srcp, dstp);
    kwpack<<<WPB, 256, 0, stream>>>(W1, wpk1);
    kwpack<<<WPB, 256, 0, stream>>>(W2, wpk2);
    ktpass<<<EB, 256, 0, stream>>>(src, dst, et, degf, T);
    kf0<<<NW, 256, 0, stream>>>(T, W0, L0, b0, degf, hpk0);

    // layer 1
    hipMemsetAsync(agg, 0, (size_t)NN * DD * 4, stream);
    kmsgm<<<1024, 256, 0, stream>>>(srcp, dstp, batchptr, hpk0, wpk1, agg);
    kfin<true, false><<<NW, 256, 0, stream>>>(agg, hpk0, L1, b1, hpk1, nullptr, nullptr);

    // layer 2
    hipMemsetAsync(agg, 0, (size_t)NN * DD * 4, stream);
    kmsgm<<<1024, 256, 0, stream>>>(srcp, dstp, batchptr, hpk1, wpk2, agg);
    kfin<false, true><<<NW, 256, 0, stream>>>(agg, hpk1, L2, b2, nullptr, embp, nuc);

    // pooling + MLP
    kgate<<<NW, 256, 0, stream>>>(embp, gatew, gateb, gate);
    kgptr<<<NB, 256, 0, stream>>>(n2g, gptr);
    kpool<<<NG, 128, 0, stream>>>(gptr, gate, embp, fpb);
    kmlp<<<NG, 128, 0, stream>>>(fpb, A1, ab1, A2, ab2, out0);
}

// Round 4
// 434.324 us; speedup vs baseline: 1.4296x; 1.3689x over previous
//
#include <hip/hip_runtime.h>
#include <cstdint>

// Problem constants (fixed by the reference)
static constexpr int NN = 50000;   // nodes
static constexpr int NE = 800000;  // edges
static constexpr int NG = 512;     // graphs
static constexpr int NR = 19;      // relations
static constexpr int DD = 64;      // hidden dim
static constexpr int EMB = 65;
static constexpr int HID = 128;
static constexpr int FP = 166;

typedef __fp16 h2 __attribute__((ext_vector_type(2)));
typedef _Float16 F16x2 __attribute__((ext_vector_type(2)));
typedef _Float16 hf8 __attribute__((ext_vector_type(8)));
typedef float f32x4 __attribute__((ext_vector_type(4)));
typedef unsigned u32x4 __attribute__((ext_vector_type(4)));
typedef int i32x4 __attribute__((ext_vector_type(4)));

union U4H8 { u32x4 u; hf8 h; };

__device__ __forceinline__ hf8 as_hf8(u32x4 u) { U4H8 c; c.u = u; return c.h; }

__device__ __forceinline__ float dot2f(unsigned a, unsigned b, float c) {
    union { unsigned u; h2 h; } ua, ub;
    ua.u = a; ub.u = b;
    return __builtin_amdgcn_fdot2(ua.h, ub.h, c, false);
}

__device__ __forceinline__ unsigned pack2(float a, float b) {
    union { h2 h; unsigned u; } r;
    r.h = __builtin_amdgcn_cvt_pkrtz(a, b);
    return r.u;
}

// packed f16x2 atomic add (2 floats per TCC atomic op)
__device__ __forceinline__ void pkAtomicAdd(unsigned* addr, float lo, float hi) {
    unsigned u = pack2(lo, hi);
#if __has_builtin(__builtin_amdgcn_global_atomic_fadd_v2f16)
    union { unsigned u; F16x2 h; } c; c.u = u;
    __builtin_amdgcn_global_atomic_fadd_v2f16((F16x2*)addr, c.h);
#else
    asm volatile("global_atomic_pk_add_f16 %0, %1, off" :: "v"(addr), "v"(u) : "memory");
#endif
}

__device__ __forceinline__ float half_at(unsigned v, int idx) {
    union { unsigned u; h2 h; } c; c.u = v;
    return (float)c.h[idx];
}

// ---------------- degree ----------------
__global__ __launch_bounds__(256) void khistdeg(const int* __restrict__ dst, int* __restrict__ degi) {
    int e = blockIdx.x * 256 + threadIdx.x;
    if (e < NE) atomicAdd(&degi[dst[e]], 1);
}

__global__ __launch_bounds__(256) void kcvtdeg(const int* __restrict__ degi, float* __restrict__ degf) {
    int n = blockIdx.x * 256 + threadIdx.x;
    if (n < NN) degf[n] = (float)degi[n];
}

// ---------------- counting sort by etype (padded to multiples of 16) ----------------
__global__ __launch_bounds__(256) void ksorthist(const int* __restrict__ et, int* __restrict__ cnt19) {
    __shared__ int lh[NR];
    if (threadIdx.x < NR) lh[threadIdx.x] = 0;
    __syncthreads();
    int e = blockIdx.x * 256 + threadIdx.x;
    if (e < NE) atomicAdd(&lh[et[e]], 1);
    __syncthreads();
    if (threadIdx.x < NR && lh[threadIdx.x]) atomicAdd(&cnt19[threadIdx.x], lh[threadIdx.x]);
}

// pbase[r] = padded bin start (multiple of 16); batchptr[r] = pbase[r]/16
__global__ void kscan19(const int* __restrict__ cnt19, int* __restrict__ pbase,
                        int* __restrict__ cur19, int* __restrict__ batchptr) {
    if (threadIdx.x == 0 && blockIdx.x == 0) {
        int run = 0;
        for (int r = 0; r < NR; ++r) {
            pbase[r] = run; cur19[r] = run; batchptr[r] = run >> 4;
            run += (cnt19[r] + 15) & ~15;
        }
        pbase[NR] = run; batchptr[NR] = run >> 4;
    }
}

__global__ __launch_bounds__(256) void kscatter(const int* __restrict__ src, const int* __restrict__ dst,
                                                const int* __restrict__ et, int* __restrict__ cur19,
                                                int* __restrict__ srcp, int* __restrict__ dstp) {
    __shared__ int lh[NR], lb[NR];
    int t = threadIdx.x;
    if (t < NR) lh[t] = 0;
    __syncthreads();
    int e = blockIdx.x * 256 + t;
    int myet = 0, loc = 0;
    if (e < NE) { myet = et[e]; loc = atomicAdd(&lh[myet], 1); }
    __syncthreads();
    if (t < NR && lh[t]) lb[t] = atomicAdd(&cur19[t], lh[t]);
    __syncthreads();
    if (e < NE) {
        int pos = lb[myet] + loc;
        srcp[pos] = src[e];
        dstp[pos] = dst[e];
    }
}

// fill padding slots with sentinel (src=NN -> zero h row, dst=0 -> adds 0.0)
__global__ __launch_bounds__(512) void kpadfill(const int* __restrict__ cnt19, const int* __restrict__ pbase,
                                                int* __restrict__ srcp, int* __restrict__ dstp) {
    int t = threadIdx.x;
    int r = t >> 4, i = t & 15;
    if (r >= NR) return;
    int cnt = cnt19[r];
    int tail = pbase[r + 1] - pbase[r] - cnt;
    if (i < tail) {
        int pos = pbase[r] + cnt + i;
        srcp[pos] = NN;
        dstp[pos] = 0;
    }
}

// ---------------- pack W into per-lane MFMA B-fragments ----------------
// Column remap for pk-atomics: fragment ct covers physical col
//   p(ct, lm) = (ct>>1)*32 + 2*lm + (ct&1)
// so lane lm's (acc0,acc1) = phys cols (2lm, 2lm+1), (acc2,acc3) = (32+2lm, 32+2lm+1).
// frag f = kh*4+ct; lane holds W[k = kh*32 + (lane>>4)*8 + j][p(ct, lane&15)], j=0..7
__global__ __launch_bounds__(256) void kwpack(const float* __restrict__ W, unsigned* __restrict__ wpk) {
    int t = blockIdx.x * 256 + threadIdx.x;
    if (t >= NR * 8 * 64) return;
    int lane = t & 63;
    int f = (t >> 6) & 7;
    int r = t >> 9;
    int kh = f >> 2, ct = f & 3;
    int kbase = kh * 32 + (lane >> 4) * 8;
    int col = (ct >> 1) * 32 + 2 * (lane & 15) + (ct & 1);
    const float* wr = W + (size_t)r * DD * DD;
    u32x4 out;
#pragma unroll
    for (int p = 0; p < 4; ++p)
        out[p] = pack2(wr[(kbase + 2 * p) * DD + col], wr[(kbase + 2 * p + 1) * DD + col]);
    *((u32x4*)wpk + t) = out;
}

// ---------------- layer 0: T[dst, et] += deg[src] ----------------
__global__ __launch_bounds__(256) void ktpass(const int* __restrict__ src, const int* __restrict__ dst,
                                              const int* __restrict__ et, const float* __restrict__ degf,
                                              float* __restrict__ T) {
    int e = blockIdx.x * 256 + threadIdx.x;
    if (e < NE) unsafeAtomicAdd(&T[dst[e] * NR + et[e]], degf[src[e]]);
}

// layer0 finalize: h0 = relu(T@W0 + deg*L0 + b0), emit packed f16
__global__ __launch_bounds__(256) void kf0(const float* __restrict__ T, const float* __restrict__ W0,
                                           const float* __restrict__ L0, const float* __restrict__ b0,
                                           const float* __restrict__ degf, unsigned* __restrict__ hpk0) {
    int lane = threadIdx.x & 63;
    int wid = __builtin_amdgcn_readfirstlane(threadIdx.x >> 6);
    int n = blockIdx.x * 4 + wid;
    if (n >= NN) return;
    float w0r[NR];
#pragma unroll
    for (int r = 0; r < NR; ++r) w0r[r] = W0[r * DD + lane];
    float acc = b0[lane] + degf[n] * L0[lane];
    const float* Trow = T + n * NR;
#pragma unroll
    for (int r = 0; r < NR; ++r) acc += Trow[r] * w0r[r];
    acc = fmaxf(acc, 0.f);
    float other = __shfl_xor(acc, 1);
    if ((lane & 1) == 0) hpk0[n * 32 + (lane >> 1)] = pack2(acc, other);
}

// ---------------- MFMA message pass ----------------
// batch = 16 same-relation edges; C[edge][col] = h[src] @ W[r]
// agg is f16x2-packed: aggh[node][32], h2 slot c = phys cols (2c, 2c+1)
__global__ __launch_bounds__(256) void kmsgm(const int* __restrict__ srcp, const int* __restrict__ dstp,
                                             const int* __restrict__ batchptr, const unsigned* __restrict__ hpk,
                                             const unsigned* __restrict__ wpk, unsigned* __restrict__ aggh) {
    const int lane = threadIdx.x & 63;
    int wid = __builtin_amdgcn_readfirstlane(threadIdx.x >> 6);
    int gw = blockIdx.x * 4 + wid;
    const int nwaves = gridDim.x * 4;
    const int totB = batchptr[NR];
    int chunk = (totB + nwaves - 1) / nwaves;
    int b0 = gw * chunk;
    int b1 = min(b0 + chunk, totB);
    if (b0 >= b1) return;

    int r = 0;
    while (batchptr[r + 1] <= b0) ++r;

    hf8 Bf[8];
    auto loadB = [&](int rr) {
        const u32x4* wq = (const u32x4*)wpk;
#pragma unroll
        for (int f = 0; f < 8; ++f) Bf[f] = as_hf8(wq[(rr * 8 + f) * 64 + lane]);
    };
    loadB(r);
    int rend = batchptr[r + 1];

    const int qk = lane >> 4;       // 0..3 k-group / row-group
    const int lm = lane & 15;       // edge-row (A) / col-pair (C)

    for (int b = b0; b < b1; ++b) {
        while (b >= rend) {
            ++r;
            rend = batchptr[r + 1];
            if (b < rend) loadB(r);
        }
        int base = b << 4;
        int s = srcp[base + lm];
        const unsigned* hr = hpk + (size_t)s * 32;
        hf8 a0 = as_hf8(*(const u32x4*)(hr + (qk << 2)));          // k in [0,32)
        hf8 a1 = as_hf8(*(const u32x4*)(hr + 16 + (qk << 2)));     // k in [32,64)
        i32x4 d4 = *(const i32x4*)(dstp + base + (qk << 2));

        f32x4 acc0 = {0.f, 0.f, 0.f, 0.f};
        f32x4 acc1 = {0.f, 0.f, 0.f, 0.f};
        f32x4 acc2 = {0.f, 0.f, 0.f, 0.f};
        f32x4 acc3 = {0.f, 0.f, 0.f, 0.f};
        acc0 = __builtin_amdgcn_mfma_f32_16x16x32_f16(a0, Bf[0], acc0, 0, 0, 0);
        acc1 = __builtin_amdgcn_mfma_f32_16x16x32_f16(a0, Bf[1], acc1, 0, 0, 0);
        acc2 = __builtin_amdgcn_mfma_f32_16x16x32_f16(a0, Bf[2], acc2, 0, 0, 0);
        acc3 = __builtin_amdgcn_mfma_f32_16x16x32_f16(a0, Bf[3], acc3, 0, 0, 0);
        acc0 = __builtin_amdgcn_mfma_f32_16x16x32_f16(a1, Bf[4], acc0, 0, 0, 0);
        acc1 = __builtin_amdgcn_mfma_f32_16x16x32_f16(a1, Bf[5], acc1, 0, 0, 0);
        acc2 = __builtin_amdgcn_mfma_f32_16x16x32_f16(a1, Bf[6], acc2, 0, 0, 0);
        acc3 = __builtin_amdgcn_mfma_f32_16x16x32_f16(a1, Bf[7], acc3, 0, 0, 0);

        // C layout: row = (lane>>4)*4 + j (edge), lane lm holds phys cols 2lm/2lm+1 (acc0/acc1)
        // and 32+2lm / 32+2lm+1 (acc2/acc3) -> one pk atomic per pair.
#pragma unroll
        for (int j = 0; j < 4; ++j) {
            unsigned* ag = aggh + (size_t)d4[j] * 32 + lm;
            pkAtomicAdd(ag, acc0[j], acc1[j]);
            pkAtomicAdd(ag + 16, acc2[j], acc3[j]);
        }
    }
}

// ---------------- finalize: out = act(aggh + h@L + b); optional gate fusion ----------------
template <bool ACT, bool WRITE_EMB>
__global__ __launch_bounds__(256) void kfin(const unsigned* __restrict__ aggh, const unsigned* __restrict__ hpk_in,
                                            const float* __restrict__ L, const float* __restrict__ bvec,
                                            unsigned* __restrict__ hpk_out, float* __restrict__ embp,
                                            const float* __restrict__ nuc, const float* __restrict__ gatew,
                                            const float* __restrict__ gateb, float* __restrict__ gate) {
    __shared__ unsigned Lp[32 * 64];
    for (int i = threadIdx.x; i < 2048; i += 256) {
        int kp = i >> 6, o = i & 63;
        Lp[i] = pack2(L[(2 * kp) * DD + o], L[(2 * kp + 1) * DD + o]);
    }
    __syncthreads();
    int lane = threadIdx.x & 63;
    int wid = __builtin_amdgcn_readfirstlane(threadIdx.x >> 6);
    int n = blockIdx.x * 4 + wid;
    if (n >= NN) return;
    float acc = half_at(aggh[(size_t)n * 32 + (lane >> 1)], lane & 1) + bvec[lane];
    const unsigned* hr = hpk_in + n * 32;
    float a0 = 0.f, a1 = 0.f, a2 = 0.f, a3 = 0.f;
#pragma unroll
    for (int k4 = 0; k4 < 8; ++k4) {
        a0 = dot2f(hr[4 * k4 + 0], Lp[(4 * k4 + 0) * 64 + lane], a0);
        a1 = dot2f(hr[4 * k4 + 1], Lp[(4 * k4 + 1) * 64 + lane], a1);
        a2 = dot2f(hr[4 * k4 + 2], Lp[(4 * k4 + 2) * 64 + lane], a2);
        a3 = dot2f(hr[4 * k4 + 3], Lp[(4 * k4 + 3) * 64 + lane], a3);
    }
    acc += (a0 + a1) + (a2 + a3);
    if (ACT) acc = fmaxf(acc, 0.f);
    if constexpr (WRITE_EMB) {
        embp[(size_t)n * EMB + lane] = acc;
        float nv = nuc[n];
        if (lane == 0) embp[(size_t)n * EMB + 64] = nv;
        // fused gate: gate[n] = sum_c emb[c]*gatew[c] + nuc*gatew[64] + gateb
        float v = acc * gatew[lane];
#pragma unroll
        for (int s = 32; s >= 1; s >>= 1) v += __shfl_xor(v, s);
        if (lane == 0) gate[n] = v + nv * gatew[64] + gateb[0];
    } else {
        float other = __shfl_xor(acc, 1);
        if ((lane & 1) == 0) hpk_out[n * 32 + (lane >> 1)] = pack2(acc, other);
    }
}

// ---------------- graph boundaries ----------------
__global__ __launch_bounds__(256) void kgptr(const int* __restrict__ n2g, int* __restrict__ gptr) {
    int n = blockIdx.x * 256 + threadIdx.x;
    if (n >= NN) return;
    int g = n2g[n];
    int gp = (n == 0) ? -1 : n2g[n - 1];
    for (int gg = gp + 1; gg <= g; ++gg) gptr[gg] = n;
    if (n == NN - 1) {
        for (int gg = g + 1; gg <= NG; ++gg) gptr[gg] = NN;
    }
}

// ---------------- attention pooling ----------------
__global__ __launch_bounds__(128) void kpool(const int* __restrict__ gptr, const float* __restrict__ gate,
                                             const float* __restrict__ emb, float* __restrict__ fpb) {
    __shared__ float red[128];
    __shared__ float wch[128];
    int g = blockIdx.x;
    int t = threadIdx.x;
    int lo = gptr[g], hi = gptr[g + 1];

    float m = -INFINITY;
    for (int i = lo + t; i < hi; i += 128) m = fmaxf(m, gate[i]);
    red[t] = m;
    __syncthreads();
    for (int s = 64; s > 0; s >>= 1) {
        if (t < s) red[t] = fmaxf(red[t], red[t + s]);
        __syncthreads();
    }
    m = red[0];
    __syncthreads();

    float sum = 0.f;
    for (int i = lo + t; i < hi; i += 128) sum += __expf(gate[i] - m);
    red[t] = sum;
    __syncthreads();
    for (int s = 64; s > 0; s >>= 1) {
        if (t < s) red[t] += red[t + s];
        __syncthreads();
    }
    float denom = red[0];
    __syncthreads();

    float acc = 0.f;
    for (int base = lo; base < hi; base += 128) {
        int i = base + t;
        wch[t] = (i < hi) ? __expf(gate[i] - m) : 0.f;
        __syncthreads();
        int cnt = min(128, hi - base);
        if (t < EMB) {
            for (int j = 0; j < cnt; ++j) acc += wch[j] * emb[(size_t)(base + j) * EMB + t];
        }
        __syncthreads();
    }
    if (t < EMB) fpb[g * EMB + t] = (hi > lo) ? acc / denom : 0.f;
}

// ---------------- attributor MLP ----------------
__global__ __launch_bounds__(128) void kmlp(const float* __restrict__ fpb, const float* __restrict__ A1,
                                            const float* __restrict__ ab1, const float* __restrict__ A2,
                                            const float* __restrict__ ab2, float* __restrict__ out) {
    __shared__ float fv[EMB];
    __shared__ float h1[HID];
    int g = blockIdx.x;
    int t = threadIdx.x;
    if (t < EMB) fv[t] = fpb[g * EMB + t];
    __syncthreads();
    float a = ab1[t];
    for (int d = 0; d < EMB; ++d) a += fv[d] * A1[d * HID + t];
    h1[t] = fmaxf(a, 0.f);
    __syncthreads();
    for (int o = t; o < FP; o += HID) {
        float v = ab2[o];
        for (int k = 0; k < HID; ++k) v += h1[k] * A2[k * FP + o];
        out[(size_t)g * FP + o] = 1.f / (1.f + __expf(-v));
    }
}

extern "C" void kernel_launch(void* const* d_in, const int* in_sizes, int n_in,
                              void* d_out, int out_size, void* d_ws, size_t ws_size,
                              hipStream_t stream) {
    const int* src = (const int*)d_in[0];
    const int* dst = (const int*)d_in[1];
    const int* et = (const int*)d_in[2];
    const int* n2g = (const int*)d_in[3];
    const float* nuc = (const float*)d_in[4];
    const float* W0 = (const float*)d_in[5];
    const float* b0 = (const float*)d_in[6];
    const float* L0 = (const float*)d_in[7];
    const float* W1 = (const float*)d_in[8];
    const float* b1 = (const float*)d_in[9];
    const float* L1 = (const float*)d_in[10];
    const float* W2 = (const float*)d_in[11];
    const float* b2 = (const float*)d_in[12];
    const float* L2 = (const float*)d_in[13];
    const float* gatew = (const float*)d_in[14];
    const float* gateb = (const float*)d_in[15];
    const float* A1 = (const float*)d_in[16];
    const float* ab1 = (const float*)d_in[17];
    const float* A2 = (const float*)d_in[18];
    const float* ab2 = (const float*)d_in[19];
    (void)in_sizes; (void)n_in; (void)out_size; (void)ws_size;

    float* out0 = (float*)d_out;                      // [G,166]
    float* embp = (float*)d_out + (size_t)NG * FP;    // [N,65]

    const int NEP = NE + NR * 16;                     // padded edge capacity

    // workspace layout
    char* w = (char*)d_ws;
    size_t off = 0;
    auto alloc = [&](size_t bytes) { size_t r = off; off = (off + bytes + 255) & ~(size_t)255; return r; };
    // zeroed span: degi, T, cnt19, hpk0, hpk1 (sentinel row NN must be 0)
    size_t o_degi = alloc(NN * 4);
    size_t o_T    = alloc((size_t)NN * NR * 4);
    size_t o_cnt  = alloc(NR * 4);
    size_t o_hpk0 = alloc((size_t)(NN + 1) * 32 * 4);
    size_t o_hpk1 = alloc((size_t)(NN + 1) * 32 * 4);
    size_t zero_span = off;
    size_t o_pb   = alloc((NR + 1) * 4);
    size_t o_cur  = alloc(NR * 4);
    size_t o_bp   = alloc((NR + 1) * 4);
    size_t o_degf = alloc(NN * 4);
    size_t o_srcp = alloc((size_t)NEP * 4);
    size_t o_dstp = alloc((size_t)NEP * 4);
    size_t o_wpk1 = alloc((size_t)NR * 8 * 64 * 16);
    size_t o_wpk2 = alloc((size_t)NR * 8 * 64 * 16);
    size_t o_agg  = alloc((size_t)NN * 32 * 4);       // f16x2-packed agg
    size_t o_gate = alloc(NN * 4);
    size_t o_gptr = alloc((NG + 1) * 4);
    size_t o_fpb  = alloc((size_t)NG * EMB * 4);

    int* degi = (int*)(w + o_degi);
    float* T = (float*)(w + o_T);
    int* cnt19 = (int*)(w + o_cnt);
    unsigned* hpk0 = (unsigned*)(w + o_hpk0);
    unsigned* hpk1 = (unsigned*)(w + o_hpk1);
    int* pbase = (int*)(w + o_pb);
    int* cur19 = (int*)(w + o_cur);
    int* batchptr = (int*)(w + o_bp);
    float* degf = (float*)(w + o_degf);
    int* srcp = (int*)(w + o_srcp);
    int* dstp = (int*)(w + o_dstp);
    unsigned* wpk1 = (unsigned*)(w + o_wpk1);
    unsigned* wpk2 = (unsigned*)(w + o_wpk2);
    unsigned* aggh = (unsigned*)(w + o_agg);
    float* gate = (float*)(w + o_gate);
    int* gptr = (int*)(w + o_gptr);
    float* fpb = (float*)(w + o_fpb);

    const int EB = (NE + 255) / 256;      // 3125
    const int NB = (NN + 255) / 256;      // 196
    const int NW = (NN + 3) / 4;          // 12500 (one node per wave, 4 waves/block)
    const int WPB = (NR * 8 * 64 + 255) / 256;

    hipMemsetAsync(w, 0, zero_span, stream);

    khistdeg<<<EB, 256, 0, stream>>>(dst, degi);
    kcvtdeg<<<NB, 256, 0, stream>>>(degi, degf);
    ksorthist<<<EB, 256, 0, stream>>>(et, cnt19);
    kscan19<<<1, 64, 0, stream>>>(cnt19, pbase, cur19, batchptr);
    kscatter<<<EB, 256, 0, stream>>>(src, dst, et, cur19, srcp, dstp);
    kpadfill<<<1, 512, 0, stream>>>(cnt19, pbase, srcp, dstp);
    kwpack<<<WPB, 256, 0, stream>>>(W1, wpk1);
    kwpack<<<WPB, 256, 0, stream>>>(W2, wpk2);
    ktpass<<<EB, 256, 0, stream>>>(src, dst, et, degf, T);
    kf0<<<NW, 256, 0, stream>>>(T, W0, L0, b0, degf, hpk0);

    // layer 1
    hipMemsetAsync(aggh, 0, (size_t)NN * 32 * 4, stream);
    kmsgm<<<1024, 256, 0, stream>>>(srcp, dstp, batchptr, hpk0, wpk1, aggh);
    kfin<true, false><<<NW, 256, 0, stream>>>(aggh, hpk0, L1, b1, hpk1, nullptr, nullptr,
                                              nullptr, nullptr, nullptr);

    // layer 2
    hipMemsetAsync(aggh, 0, (size_t)NN * 32 * 4, stream);
    kmsgm<<<1024, 256, 0, stream>>>(srcp, dstp, batchptr, hpk1, wpk2, aggh);
    kfin<false, true><<<NW, 256, 0, stream>>>(aggh, hpk1, L2, b2, nullptr, embp, nuc,
                                              gatew, gateb, gate);

    // pooling + MLP
    kgptr<<<NB, 256, 0, stream>>>(n2g, gptr);
    kpool<<<NG, 128, 0, stream>>>(gptr, gate, embp, fpb);
    kmlp<<<NG, 128, 0, stream>>>(fpb, A1, ab1, A2, ab2, out0);
}